// Round 2
// baseline (466.679 us; speedup 1.0000x reference)
//
#include <hip/hip_runtime.h>
#include <math.h>

#define EPS 1e-5f
#define KEXP 4.8089834696298780f  // log2(e)/0.3 : exp(x/h) == exp2(x*KEXP)

typedef short short8 __attribute__((ext_vector_type(8)));
typedef float f32x16 __attribute__((ext_vector_type(16)));

static __device__ __forceinline__ unsigned short f2bf(float x) {
  unsigned int b = __float_as_uint(x);
  b += 0x7FFFu + ((b >> 16) & 1u);  // RNE
  return (unsigned short)(b >> 16);
}
static __device__ __forceinline__ unsigned encf(float f) {
  unsigned b = __float_as_uint(f);
  return (b & 0x80000000u) ? ~b : (b | 0x80000000u);
}
static __device__ __forceinline__ float decf(unsigned u) {
  return (u & 0x80000000u) ? __uint_as_float(u & 0x7FFFFFFFu)
                           : __uint_as_float(~u);
}

// async global->LDS, 16B per lane (lane l lands at lds_base + 16*l)
static __device__ __forceinline__ void dma16(const uint4* g, uint4* l) {
  __builtin_amdgcn_global_load_lds(
      (const __attribute__((address_space(1))) unsigned int*)g,
      (__attribute__((address_space(3))) unsigned int*)l, 16, 0, 0);
}

// ---------------------------------------------------------------------------
// prep: normalize column j (over C), cast bf16, write 32x32x16-fragment-blocked:
//   (j,c) -> uint4 idx ((j>>5)*KC + (c>>4))*64 + ((c>>3)&1)*32 + (j&31)
// KC = C/16. Fragment (64 uint4 = 1KB) = 32-row(j) x 16-k tile; lane l holds
// row l&31, k = (l>>5)*8..+8 (verified layout, rounds 0-1 pass).
// Each thread handles 4 consecutive j -> float4 global loads, 64B stores.
// ---------------------------------------------------------------------------
template <int C, int HW>
__device__ __forceinline__ void prep_body4(const float* __restrict__ f,
                                           uint4* __restrict__ out, int g4) {
  constexpr int PS = HW / 4;
  int b = g4 / PS, jj = g4 - b * PS;
  int j = jj * 4;
  const float* p = f + (size_t)b * C * HW + j;
  float ssq[4] = {0.f, 0.f, 0.f, 0.f};
  for (int c = 0; c < C; ++c) {
    float4 v = *(const float4*)&p[(size_t)c * HW];
    ssq[0] = fmaf(v.x, v.x, ssq[0]);
    ssq[1] = fmaf(v.y, v.y, ssq[1]);
    ssq[2] = fmaf(v.z, v.z, ssq[2]);
    ssq[3] = fmaf(v.w, v.w, ssq[3]);
  }
  float inv[4];
#pragma unroll
  for (int k = 0; k < 4; ++k) inv[k] = 1.0f / (sqrtf(ssq[k]) + EPS);
  constexpr int KC = C >> 4;
  uint4* ob = out + (size_t)b * (HW >> 5) * KC * 64 + (size_t)(j >> 5) * KC * 64 + (j & 31);
  for (int c0 = 0; c0 < C; c0 += 8) {
    unsigned w[4][4];
#pragma unroll
    for (int h = 0; h < 4; ++h) {
      float4 v0 = *(const float4*)&p[(size_t)(c0 + 2 * h) * HW];
      float4 v1 = *(const float4*)&p[(size_t)(c0 + 2 * h + 1) * HW];
      const float* a0 = &v0.x;
      const float* a1 = &v1.x;
#pragma unroll
      for (int k = 0; k < 4; ++k)
        w[k][h] = (unsigned)f2bf(a0[k] * inv[k]) | ((unsigned)f2bf(a1[k] * inv[k]) << 16);
    }
    size_t koff = (size_t)(c0 >> 4) * 64 + ((c0 >> 3) & 1) * 32;
#pragma unroll
    for (int k = 0; k < 4; ++k)
      ob[koff + k] = make_uint4(w[k][0], w[k][1], w[k][2], w[k][3]);
  }
}

// prep + init of dE (0xFF), S (0), out (0) in one launch. 96 blocks.
__global__ __launch_bounds__(256) void prep_all(
    const float* __restrict__ fx1, uint4* __restrict__ fx1B,
    const float* __restrict__ fy1, uint4* __restrict__ fy1B,
    const float* __restrict__ fx2, uint4* __restrict__ fx2B,
    const float* __restrict__ fy2, uint4* __restrict__ fy2B,
    unsigned* __restrict__ dE, float* __restrict__ S, float* __restrict__ out) {
  int bid = blockIdx.x;
  if (bid < 32)       prep_body4<128, 4096>(fx1, fx1B, bid * 256 + threadIdx.x);
  else if (bid < 64)  prep_body4<128, 4096>(fy1, fy1B, (bid - 32) * 256 + threadIdx.x);
  else if (bid < 72)  prep_body4<256, 1024>(fx2, fx2B, (bid - 64) * 256 + threadIdx.x);
  else if (bid < 80)  prep_body4<256, 1024>(fy2, fy2B, (bid - 72) * 256 + threadIdx.x);
  else {
    int t = (bid - 80) * 256 + threadIdx.x;  // 16 blocks -> 4096 threads
    for (int k = t; k < 8 * (4096 + 1024); k += 4096) {
      dE[k] = 0xFFFFFFFFu;
      S[k] = 0.f;
    }
    if (t == 0) out[0] = 0.f;
  }
}

// ---------------------------------------------------------------------------
// passA body: 4 waves, each owning TI 32-wide i-tiles; j staged via
// global_load_lds, double-buffered, JTPB j-tiles per barrier (amortizes the
// vmcnt(0)+barrier drain). 32x32x16 MFMA. Element-wise f32x16 running max
// (independent ops; no 16-deep serial chain per step).
// ---------------------------------------------------------------------------
template <int HW, int C, int TI, int JSPLIT, int JTPB>
__device__ __forceinline__ void passA_body(
    const uint4* __restrict__ fxB, const uint4* __restrict__ fyB,
    unsigned* __restrict__ dminEnc, int bid, uint4* __restrict__ smem) {
  constexpr int KC = C / 16;        // 16-k chunks (1 KB fragments)
  constexpr int KCT = KC * JTPB;    // chunks staged per barrier
  constexpr int JB = HW / 32;       // 32-wide j-tiles per sample
  constexpr int IBW = 4 * TI;       // 32-wide i-tiles per block
  constexpr int JPS = JB / JSPLIT;  // j-tiles per block
  constexpr int NST = JPS / JTPB;   // barrier steps
  const int lane = threadIdx.x & 63, wv = threadIdx.x >> 6;
  const int sample = bid & 7;       // XCD affinity
  const int rem = bid >> 3;
  const int ib = (rem / JSPLIT) * IBW + wv * TI;
  const int jt0 = (rem % JSPLIT) * JPS;
  const size_t sOff = (size_t)sample * JB * KC * 64;
  const uint4* fx = fxB + sOff;
  const uint4* fy = fyB + sOff;

  auto stage = [&](int jt, int buf) {  // stages JTPB consecutive tiles (16 KB)
    const uint4* g = fy + (size_t)jt * KC * 64;
#pragma unroll
    for (int r = 0; r < KCT / 4; ++r) {
      const int t = threadIdx.x + r * 256;
      dma16(g + t, &smem[buf * (KCT * 64) + t]);
    }
  };

  stage(jt0, 0);  // prologue DMA

  short8 bf[TI][KC];  // persistent fx fragments (B operand, i = cols of D)
#pragma unroll
  for (int ti = 0; ti < TI; ++ti)
#pragma unroll
    for (int kc = 0; kc < KC; ++kc) {
      uint4 t = fx[(size_t)((ib + ti) * KC + kc) * 64 + lane];
      bf[ti][kc] = *(short8*)&t;
    }

  f32x16 rmax[TI];
#pragma unroll
  for (int ti = 0; ti < TI; ++ti)
#pragma unroll
    for (int r = 0; r < 16; ++r) rmax[ti][r] = -1e30f;

  for (int s = 0; s < NST; ++s) {
    const int cur = s & 1;
    __syncthreads();                       // tiles ready; prev reads done
    if (s + 1 < NST) stage(jt0 + (s + 1) * JTPB, cur ^ 1);
    const uint4* sb = &smem[cur * (KCT * 64)];

#pragma unroll
    for (int t2 = 0; t2 < JTPB; ++t2) {
      f32x16 acc[TI];
#pragma unroll
      for (int ti = 0; ti < TI; ++ti)
#pragma unroll
        for (int r = 0; r < 16; ++r) acc[ti][r] = 0.f;
      __builtin_amdgcn_s_setprio(1);
#pragma unroll
      for (int kc = 0; kc < KC; ++kc) {
        uint4 t = sb[(t2 * KC + kc) * 64 + lane];
        short8 a = *(short8*)&t;
#pragma unroll
        for (int ti = 0; ti < TI; ++ti)
          acc[ti] = __builtin_amdgcn_mfma_f32_32x32x16_bf16(a, bf[ti][kc], acc[ti], 0, 0, 0);
      }
      __builtin_amdgcn_s_setprio(0);
#pragma unroll
      for (int ti = 0; ti < TI; ++ti)
#pragma unroll
        for (int r = 0; r < 16; ++r) rmax[ti][r] = fmaxf(rmax[ti][r], acc[ti][r]);
    }
  }

  // rows j live in regs + lane bit5 -> one xor-32 hop; cols i = lane&31
#pragma unroll
  for (int ti = 0; ti < TI; ++ti) {
    float v = -1e30f;
#pragma unroll
    for (int r = 0; r < 16; ++r) v = fmaxf(v, rmax[ti][r]);
    v = fmaxf(v, __shfl_xor(v, 32));
    if (lane < 32)
      atomicMin(&dminEnc[(size_t)sample * HW + (ib + ti) * 32 + lane],
                encf(1.0f - v));
  }
}

// ---------------------------------------------------------------------------
// passB body: recompute dots, partial sum_j exp2(c0 + sim*c1), element-wise
// f32x16 partial sums (independent adds).
// ---------------------------------------------------------------------------
template <int HW, int C, int TI, int JSPLIT, int JTPB>
__device__ __forceinline__ void passB_body(
    const uint4* __restrict__ fxB, const uint4* __restrict__ fyB,
    const unsigned* __restrict__ dminEnc, float* __restrict__ Ssum,
    int bid, uint4* __restrict__ smem) {
  constexpr int KC = C / 16;
  constexpr int KCT = KC * JTPB;
  constexpr int JB = HW / 32;
  constexpr int IBW = 4 * TI;
  constexpr int JPS = JB / JSPLIT;
  constexpr int NST = JPS / JTPB;
  const int lane = threadIdx.x & 63, wv = threadIdx.x >> 6;
  const int sample = bid & 7;
  const int rem = bid >> 3;
  const int ib = (rem / JSPLIT) * IBW + wv * TI;
  const int jt0 = (rem % JSPLIT) * JPS;
  const size_t sOff = (size_t)sample * JB * KC * 64;
  const uint4* fx = fxB + sOff;
  const uint4* fy = fyB + sOff;

  auto stage = [&](int jt, int buf) {
    const uint4* g = fy + (size_t)jt * KC * 64;
#pragma unroll
    for (int r = 0; r < KCT / 4; ++r) {
      const int t = threadIdx.x + r * 256;
      dma16(g + t, &smem[buf * (KCT * 64) + t]);
    }
  };

  stage(jt0, 0);

  short8 bf[TI][KC];
#pragma unroll
  for (int ti = 0; ti < TI; ++ti)
#pragma unroll
    for (int kc = 0; kc < KC; ++kc) {
      uint4 t = fx[(size_t)((ib + ti) * KC + kc) * 64 + lane];
      bf[ti][kc] = *(short8*)&t;
    }

  float c0v[TI], c1v[TI];
#pragma unroll
  for (int ti = 0; ti < TI; ++ti) {
    float dmin = decf(dminEnc[(size_t)sample * HW + (ib + ti) * 32 + (lane & 31)]);
    float dinv = 1.0f / (dmin + EPS);
    c1v[ti] = dinv * KEXP;
    c0v[ti] = (1.0f - dinv) * KEXP;
  }

  f32x16 rsum[TI];
#pragma unroll
  for (int ti = 0; ti < TI; ++ti)
#pragma unroll
    for (int r = 0; r < 16; ++r) rsum[ti][r] = 0.f;

  for (int s = 0; s < NST; ++s) {
    const int cur = s & 1;
    __syncthreads();
    if (s + 1 < NST) stage(jt0 + (s + 1) * JTPB, cur ^ 1);
    const uint4* sb = &smem[cur * (KCT * 64)];

#pragma unroll
    for (int t2 = 0; t2 < JTPB; ++t2) {
      f32x16 acc[TI];
#pragma unroll
      for (int ti = 0; ti < TI; ++ti)
#pragma unroll
        for (int r = 0; r < 16; ++r) acc[ti][r] = 0.f;
      __builtin_amdgcn_s_setprio(1);
#pragma unroll
      for (int kc = 0; kc < KC; ++kc) {
        uint4 t = sb[(t2 * KC + kc) * 64 + lane];
        short8 a = *(short8*)&t;
#pragma unroll
        for (int ti = 0; ti < TI; ++ti)
          acc[ti] = __builtin_amdgcn_mfma_f32_32x32x16_bf16(a, bf[ti][kc], acc[ti], 0, 0, 0);
      }
      __builtin_amdgcn_s_setprio(0);
#pragma unroll
      for (int ti = 0; ti < TI; ++ti)
#pragma unroll
        for (int r = 0; r < 16; ++r)
          rsum[ti][r] += __builtin_amdgcn_exp2f(fmaf(acc[ti][r], c1v[ti], c0v[ti]));
    }
  }

#pragma unroll
  for (int ti = 0; ti < TI; ++ti) {
    float v = 0.f;
#pragma unroll
    for (int r = 0; r < 16; ++r) v += rsum[ti][r];
    v += __shfl_xor(v, 32);
    if (lane < 32)
      atomicAdd(&Ssum[(size_t)sample * HW + (ib + ti) * 32 + lane], v);
  }
}

// ---------------------------------------------------------------------------
// Fused launches: layer1 (1024 blocks) + layer2 (512 blocks) in one grid.
// LDS: 32KB/block dbuf (16KB per barrier-step both layers).
// layer1: TI=2, JSPLIT=8, JTPB=2 -> 8 barrier steps of 64 j
// layer2: TI=1, JSPLIT=8, JTPB=1 -> 4 barrier steps of 32 j
// ---------------------------------------------------------------------------
__global__ __launch_bounds__(256, 4) void passA_all(
    const uint4* __restrict__ fx1B, const uint4* __restrict__ fy1B,
    unsigned* __restrict__ dE1,
    const uint4* __restrict__ fx2B, const uint4* __restrict__ fy2B,
    unsigned* __restrict__ dE2) {
  __shared__ uint4 smem[2048];  // 32 KB
  if (blockIdx.x < 1024)
    passA_body<4096, 128, 2, 8, 2>(fx1B, fy1B, dE1, blockIdx.x, smem);
  else
    passA_body<1024, 256, 1, 8, 1>(fx2B, fy2B, dE2, blockIdx.x - 1024, smem);
}

__global__ __launch_bounds__(256, 4) void passB_all(
    const uint4* __restrict__ fx1B, const uint4* __restrict__ fy1B,
    const unsigned* __restrict__ dE1, float* __restrict__ S1,
    const uint4* __restrict__ fx2B, const uint4* __restrict__ fy2B,
    const unsigned* __restrict__ dE2, float* __restrict__ S2) {
  __shared__ uint4 smem[2048];
  if (blockIdx.x < 1024)
    passB_body<4096, 128, 2, 8, 2>(fx1B, fy1B, dE1, S1, blockIdx.x, smem);
  else
    passB_body<1024, 256, 1, 8, 1>(fx2B, fy2B, dE2, S2, blockIdx.x - 1024, smem);
}

// ---------------------------------------------------------------------------
// reduce_out: one block per sample; atomicAdd(-log(cx+EPS)/16) into out[0].
// ---------------------------------------------------------------------------
__global__ __launch_bounds__(256) void reduce_out(
    const unsigned* __restrict__ dE1, const float* __restrict__ S1,
    const unsigned* __restrict__ dE2, const float* __restrict__ S2,
    float* __restrict__ out) {
  const int s = blockIdx.x;
  const unsigned* dE;
  const float* Sp;
  int HW;
  if (s < 8) { dE = dE1 + (size_t)s * 4096; Sp = S1 + (size_t)s * 4096; HW = 4096; }
  else       { dE = dE2 + (size_t)(s - 8) * 1024; Sp = S2 + (size_t)(s - 8) * 1024; HW = 1024; }
  float t = 0.f;
  for (int i = threadIdx.x; i < HW; i += 256) {
    float dmin = decf(dE[i]);
    float dinv = 1.0f / (dmin + EPS);
    float wmx = __builtin_amdgcn_exp2f((1.0f - dmin * dinv) * KEXP);
    t += wmx / (Sp[i] + EPS);
  }
  __shared__ float red[4];
  t += __shfl_xor(t, 1);  t += __shfl_xor(t, 2);  t += __shfl_xor(t, 4);
  t += __shfl_xor(t, 8);  t += __shfl_xor(t, 16); t += __shfl_xor(t, 32);
  if ((threadIdx.x & 63) == 0) red[threadIdx.x >> 6] = t;
  __syncthreads();
  if (threadIdx.x == 0) {
    float cx = (red[0] + red[1] + red[2] + red[3]) / (float)HW;
    atomicAdd(out, -logf(cx + EPS) * (1.0f / 16.0f));
  }
}

extern "C" void kernel_launch(void* const* d_in, const int* in_sizes, int n_in,
                              void* d_out, int out_size, void* d_ws, size_t ws_size,
                              hipStream_t stream) {
  const float* fx1 = (const float*)d_in[0];  // (8,128,64,64)
  const float* fy1 = (const float*)d_in[1];
  const float* fx2 = (const float*)d_in[2];  // (8,256,32,32)
  const float* fy2 = (const float*)d_in[3];
  float* out = (float*)d_out;

  const int B = 8, HW1 = 4096, HW2 = 1024;

  char* w = (char*)d_ws;
  unsigned* dE1 = (unsigned*)w;                      // 8*4096 u32
  unsigned* dE2 = dE1 + (size_t)B * HW1;             // 8*1024 u32
  float*    S1  = (float*)(dE2 + (size_t)B * HW2);   // 8*4096 f
  float*    S2  = S1 + (size_t)B * HW1;              // 8*1024 f
  uint4*    fx1B = (uint4*)((char*)(S2 + (size_t)B * HW2) + 1024);
  const size_t n1 = (size_t)B * (HW1 / 32) * (128 / 16) * 64;  // 8 MB
  const size_t n2 = (size_t)B * (HW2 / 32) * (256 / 16) * 64;  // 4 MB
  uint4* fy1B = fx1B + n1;
  uint4* fx2B = fy1B + n1;
  uint4* fy2B = fx2B + n2;   // total ~24.4 MB

  prep_all<<<96, 256, 0, stream>>>(fx1, fx1B, fy1, fy1B, fx2, fx2B, fy2, fy2B,
                                   dE1, S1, out);

  passA_all<<<1536, 256, 0, stream>>>(fx1B, fy1B, dE1, fx2B, fy2B, dE2);
  passB_all<<<1536, 256, 0, stream>>>(fx1B, fy1B, dE1, S1, fx2B, fy2B, dE2, S2);

  reduce_out<<<16, 256, 0, stream>>>(dE1, S1, dE2, S2, out);
}

// Round 3
// 255.251 us; speedup vs baseline: 1.8283x; 1.8283x over previous
//
#include <hip/hip_runtime.h>
#include <math.h>

#define EPS 1e-5f
#define KEXP 4.8089834696298780f  // log2(e)/0.3 : exp(x/h) == exp2(x*KEXP)

typedef short short8 __attribute__((ext_vector_type(8)));
typedef float f32x16 __attribute__((ext_vector_type(16)));

static __device__ __forceinline__ unsigned short f2bf(float x) {
  unsigned int b = __float_as_uint(x);
  b += 0x7FFFu + ((b >> 16) & 1u);  // RNE
  return (unsigned short)(b >> 16);
}
static __device__ __forceinline__ unsigned encf(float f) {
  unsigned b = __float_as_uint(f);
  return (b & 0x80000000u) ? ~b : (b | 0x80000000u);
}
static __device__ __forceinline__ float decf(unsigned u) {
  return (u & 0x80000000u) ? __uint_as_float(u & 0x7FFFFFFFu)
                           : __uint_as_float(~u);
}

// async global->LDS, 16B per lane (lane l lands at lds_base + 16*l)
static __device__ __forceinline__ void dma16(const uint4* g, uint4* l) {
  __builtin_amdgcn_global_load_lds(
      (const __attribute__((address_space(1))) unsigned int*)g,
      (__attribute__((address_space(3))) unsigned int*)l, 16, 0, 0);
}

// ---------------------------------------------------------------------------
// prep: normalize column j (over C), cast bf16, write 32x32x16-fragment-blocked:
//   (j,c) -> uint4 idx ((j>>5)*KC + (c>>4))*64 + ((c>>3)&1)*32 + (j&31)
// KC = C/16. Fragment (64 uint4 = 1KB) = 32-row(j) x 16-k tile; lane l holds
// row l&31, k = (l>>5)*8..+8 (verified layout, rounds 0-2 pass).
// Each thread handles 4 consecutive j -> float4 global loads, 64B stores.
// ---------------------------------------------------------------------------
template <int C, int HW>
__device__ __forceinline__ void prep_body4(const float* __restrict__ f,
                                           uint4* __restrict__ out, int g4) {
  constexpr int PS = HW / 4;
  int b = g4 / PS, jj = g4 - b * PS;
  int j = jj * 4;
  const float* p = f + (size_t)b * C * HW + j;
  float ssq[4] = {0.f, 0.f, 0.f, 0.f};
  for (int c = 0; c < C; ++c) {
    float4 v = *(const float4*)&p[(size_t)c * HW];
    ssq[0] = fmaf(v.x, v.x, ssq[0]);
    ssq[1] = fmaf(v.y, v.y, ssq[1]);
    ssq[2] = fmaf(v.z, v.z, ssq[2]);
    ssq[3] = fmaf(v.w, v.w, ssq[3]);
  }
  float inv[4];
#pragma unroll
  for (int k = 0; k < 4; ++k) inv[k] = 1.0f / (sqrtf(ssq[k]) + EPS);
  constexpr int KC = C >> 4;
  uint4* ob = out + (size_t)b * (HW >> 5) * KC * 64 + (size_t)(j >> 5) * KC * 64 + (j & 31);
  for (int c0 = 0; c0 < C; c0 += 8) {
    unsigned w[4][4];
#pragma unroll
    for (int h = 0; h < 4; ++h) {
      float4 v0 = *(const float4*)&p[(size_t)(c0 + 2 * h) * HW];
      float4 v1 = *(const float4*)&p[(size_t)(c0 + 2 * h + 1) * HW];
      const float* a0 = &v0.x;
      const float* a1 = &v1.x;
#pragma unroll
      for (int k = 0; k < 4; ++k)
        w[k][h] = (unsigned)f2bf(a0[k] * inv[k]) | ((unsigned)f2bf(a1[k] * inv[k]) << 16);
    }
    size_t koff = (size_t)(c0 >> 4) * 64 + ((c0 >> 3) & 1) * 32;
#pragma unroll
    for (int k = 0; k < 4; ++k)
      ob[koff + k] = make_uint4(w[k][0], w[k][1], w[k][2], w[k][3]);
  }
}

// prep + init of dE (0xFF), S (0), out (0) in one launch. 96 blocks.
__global__ __launch_bounds__(256) void prep_all(
    const float* __restrict__ fx1, uint4* __restrict__ fx1B,
    const float* __restrict__ fy1, uint4* __restrict__ fy1B,
    const float* __restrict__ fx2, uint4* __restrict__ fx2B,
    const float* __restrict__ fy2, uint4* __restrict__ fy2B,
    unsigned* __restrict__ dE, float* __restrict__ S, float* __restrict__ out) {
  int bid = blockIdx.x;
  if (bid < 32)       prep_body4<128, 4096>(fx1, fx1B, bid * 256 + threadIdx.x);
  else if (bid < 64)  prep_body4<128, 4096>(fy1, fy1B, (bid - 32) * 256 + threadIdx.x);
  else if (bid < 72)  prep_body4<256, 1024>(fx2, fx2B, (bid - 64) * 256 + threadIdx.x);
  else if (bid < 80)  prep_body4<256, 1024>(fy2, fy2B, (bid - 72) * 256 + threadIdx.x);
  else {
    int t = (bid - 80) * 256 + threadIdx.x;  // 16 blocks -> 4096 threads
    for (int k = t; k < 8 * (4096 + 1024); k += 4096) {
      dE[k] = 0xFFFFFFFFu;
      S[k] = 0.f;
    }
    if (t == 0) out[0] = 0.f;
  }
}

// ---------------------------------------------------------------------------
// passA body: 4 waves, each owning TI 32-wide i-tiles; j staged via
// global_load_lds, double-buffered, JTPB j-tiles per barrier (amortizes the
// vmcnt(0)+barrier drain; LDS-only cost). 32x32x16 MFMA.
// REGISTER DISCIPLINE (round-2 spill lesson): only bf[TI][KC] (32 VGPR) and
// acc[TI] (32, AGPR-resident) are wide-live; each j-tile's acc reduces to a
// scalar immediately. No f32x16 accumulators held across steps.
// ---------------------------------------------------------------------------
template <int HW, int C, int TI, int JSPLIT, int JTPB>
__device__ __forceinline__ void passA_body(
    const uint4* __restrict__ fxB, const uint4* __restrict__ fyB,
    unsigned* __restrict__ dminEnc, int bid, uint4* __restrict__ smem) {
  constexpr int KC = C / 16;        // 16-k chunks (1 KB fragments)
  constexpr int KCT = KC * JTPB;    // chunks staged per barrier
  constexpr int JB = HW / 32;       // 32-wide j-tiles per sample
  constexpr int IBW = 4 * TI;       // 32-wide i-tiles per block
  constexpr int JPS = JB / JSPLIT;  // j-tiles per block
  constexpr int NST = JPS / JTPB;   // barrier steps
  const int lane = threadIdx.x & 63, wv = threadIdx.x >> 6;
  const int sample = bid & 7;       // XCD affinity
  const int rem = bid >> 3;
  const int ib = (rem / JSPLIT) * IBW + wv * TI;
  const int jt0 = (rem % JSPLIT) * JPS;
  const size_t sOff = (size_t)sample * JB * KC * 64;
  const uint4* fx = fxB + sOff;
  const uint4* fy = fyB + sOff;

  auto stage = [&](int jt, int buf) {  // stages JTPB consecutive tiles
    const uint4* g = fy + (size_t)jt * KC * 64;
#pragma unroll
    for (int r = 0; r < KCT / 4; ++r) {
      const int t = threadIdx.x + r * 256;
      dma16(g + t, &smem[buf * (KCT * 64) + t]);
    }
  };

  stage(jt0, 0);  // prologue DMA

  short8 bf[TI][KC];  // persistent fx fragments (B operand, i = cols of D)
#pragma unroll
  for (int ti = 0; ti < TI; ++ti)
#pragma unroll
    for (int kc = 0; kc < KC; ++kc) {
      uint4 t = fx[(size_t)((ib + ti) * KC + kc) * 64 + lane];
      bf[ti][kc] = *(short8*)&t;
    }

  float smax[TI];
#pragma unroll
  for (int ti = 0; ti < TI; ++ti) smax[ti] = -1e30f;

  for (int s = 0; s < NST; ++s) {
    const int cur = s & 1;
    __syncthreads();                       // tiles ready; prev reads done
    if (s + 1 < NST) stage(jt0 + (s + 1) * JTPB, cur ^ 1);
    const uint4* sb = &smem[cur * (KCT * 64)];

#pragma unroll
    for (int t2 = 0; t2 < JTPB; ++t2) {
      f32x16 acc[TI];
#pragma unroll
      for (int ti = 0; ti < TI; ++ti)
#pragma unroll
        for (int r = 0; r < 16; ++r) acc[ti][r] = 0.f;
      __builtin_amdgcn_s_setprio(1);
#pragma unroll
      for (int kc = 0; kc < KC; ++kc) {
        uint4 t = sb[(t2 * KC + kc) * 64 + lane];
        short8 a = *(short8*)&t;
#pragma unroll
        for (int ti = 0; ti < TI; ++ti)
          acc[ti] = __builtin_amdgcn_mfma_f32_32x32x16_bf16(a, bf[ti][kc], acc[ti], 0, 0, 0);
      }
      __builtin_amdgcn_s_setprio(0);
      // immediate scalar reduction: acc dies here, no wide carry across steps
#pragma unroll
      for (int ti = 0; ti < TI; ++ti)
#pragma unroll
        for (int r = 0; r < 16; ++r) smax[ti] = fmaxf(smax[ti], acc[ti][r]);
    }
  }

  // rows j live in regs + lane bit5 -> one xor-32 hop; cols i = lane&31
#pragma unroll
  for (int ti = 0; ti < TI; ++ti) {
    float v = smax[ti];
    v = fmaxf(v, __shfl_xor(v, 32));
    if (lane < 32)
      atomicMin(&dminEnc[(size_t)sample * HW + (ib + ti) * 32 + lane],
                encf(1.0f - v));
  }
}

// ---------------------------------------------------------------------------
// passB body: recompute dots, partial sum_j exp2(c0 + sim*c1); same register
// discipline (scalar ssum[TI], acc reduced per j-tile).
// ---------------------------------------------------------------------------
template <int HW, int C, int TI, int JSPLIT, int JTPB>
__device__ __forceinline__ void passB_body(
    const uint4* __restrict__ fxB, const uint4* __restrict__ fyB,
    const unsigned* __restrict__ dminEnc, float* __restrict__ Ssum,
    int bid, uint4* __restrict__ smem) {
  constexpr int KC = C / 16;
  constexpr int KCT = KC * JTPB;
  constexpr int JB = HW / 32;
  constexpr int IBW = 4 * TI;
  constexpr int JPS = JB / JSPLIT;
  constexpr int NST = JPS / JTPB;
  const int lane = threadIdx.x & 63, wv = threadIdx.x >> 6;
  const int sample = bid & 7;
  const int rem = bid >> 3;
  const int ib = (rem / JSPLIT) * IBW + wv * TI;
  const int jt0 = (rem % JSPLIT) * JPS;
  const size_t sOff = (size_t)sample * JB * KC * 64;
  const uint4* fx = fxB + sOff;
  const uint4* fy = fyB + sOff;

  auto stage = [&](int jt, int buf) {
    const uint4* g = fy + (size_t)jt * KC * 64;
#pragma unroll
    for (int r = 0; r < KCT / 4; ++r) {
      const int t = threadIdx.x + r * 256;
      dma16(g + t, &smem[buf * (KCT * 64) + t]);
    }
  };

  stage(jt0, 0);

  short8 bf[TI][KC];
#pragma unroll
  for (int ti = 0; ti < TI; ++ti)
#pragma unroll
    for (int kc = 0; kc < KC; ++kc) {
      uint4 t = fx[(size_t)((ib + ti) * KC + kc) * 64 + lane];
      bf[ti][kc] = *(short8*)&t;
    }

  float c0v[TI], c1v[TI];
#pragma unroll
  for (int ti = 0; ti < TI; ++ti) {
    float dmin = decf(dminEnc[(size_t)sample * HW + (ib + ti) * 32 + (lane & 31)]);
    float dinv = 1.0f / (dmin + EPS);
    c1v[ti] = dinv * KEXP;
    c0v[ti] = (1.0f - dinv) * KEXP;
  }

  float ssum[TI];
#pragma unroll
  for (int ti = 0; ti < TI; ++ti) ssum[ti] = 0.f;

  for (int s = 0; s < NST; ++s) {
    const int cur = s & 1;
    __syncthreads();
    if (s + 1 < NST) stage(jt0 + (s + 1) * JTPB, cur ^ 1);
    const uint4* sb = &smem[cur * (KCT * 64)];

#pragma unroll
    for (int t2 = 0; t2 < JTPB; ++t2) {
      f32x16 acc[TI];
#pragma unroll
      for (int ti = 0; ti < TI; ++ti)
#pragma unroll
        for (int r = 0; r < 16; ++r) acc[ti][r] = 0.f;
      __builtin_amdgcn_s_setprio(1);
#pragma unroll
      for (int kc = 0; kc < KC; ++kc) {
        uint4 t = sb[(t2 * KC + kc) * 64 + lane];
        short8 a = *(short8*)&t;
#pragma unroll
        for (int ti = 0; ti < TI; ++ti)
          acc[ti] = __builtin_amdgcn_mfma_f32_32x32x16_bf16(a, bf[ti][kc], acc[ti], 0, 0, 0);
      }
      __builtin_amdgcn_s_setprio(0);
#pragma unroll
      for (int ti = 0; ti < TI; ++ti)
#pragma unroll
        for (int r = 0; r < 16; ++r)
          ssum[ti] += __builtin_amdgcn_exp2f(fmaf(acc[ti][r], c1v[ti], c0v[ti]));
    }
  }

#pragma unroll
  for (int ti = 0; ti < TI; ++ti) {
    float v = ssum[ti];
    v += __shfl_xor(v, 32);
    if (lane < 32)
      atomicAdd(&Ssum[(size_t)sample * HW + (ib + ti) * 32 + lane], v);
  }
}

// ---------------------------------------------------------------------------
// Fused launches: layer1 (1024 blocks) + layer2 (512 blocks) in one grid.
// LDS: 32KB/block dbuf (16KB per barrier-step both layers).
// layer1: TI=2, JSPLIT=8, JTPB=2 -> 8 barrier steps of 64 j
// layer2: TI=1, JSPLIT=8, JTPB=1 -> 4 barrier steps of 32 j
// ---------------------------------------------------------------------------
__global__ __launch_bounds__(256, 4) void passA_all(
    const uint4* __restrict__ fx1B, const uint4* __restrict__ fy1B,
    unsigned* __restrict__ dE1,
    const uint4* __restrict__ fx2B, const uint4* __restrict__ fy2B,
    unsigned* __restrict__ dE2) {
  __shared__ uint4 smem[2048];  // 32 KB
  if (blockIdx.x < 1024)
    passA_body<4096, 128, 2, 8, 2>(fx1B, fy1B, dE1, blockIdx.x, smem);
  else
    passA_body<1024, 256, 1, 8, 1>(fx2B, fy2B, dE2, blockIdx.x - 1024, smem);
}

__global__ __launch_bounds__(256, 4) void passB_all(
    const uint4* __restrict__ fx1B, const uint4* __restrict__ fy1B,
    const unsigned* __restrict__ dE1, float* __restrict__ S1,
    const uint4* __restrict__ fx2B, const uint4* __restrict__ fy2B,
    const unsigned* __restrict__ dE2, float* __restrict__ S2) {
  __shared__ uint4 smem[2048];
  if (blockIdx.x < 1024)
    passB_body<4096, 128, 2, 8, 2>(fx1B, fy1B, dE1, S1, blockIdx.x, smem);
  else
    passB_body<1024, 256, 1, 8, 1>(fx2B, fy2B, dE2, S2, blockIdx.x - 1024, smem);
}

// ---------------------------------------------------------------------------
// reduce_out: one block per sample; atomicAdd(-log(cx+EPS)/16) into out[0].
// ---------------------------------------------------------------------------
__global__ __launch_bounds__(256) void reduce_out(
    const unsigned* __restrict__ dE1, const float* __restrict__ S1,
    const unsigned* __restrict__ dE2, const float* __restrict__ S2,
    float* __restrict__ out) {
  const int s = blockIdx.x;
  const unsigned* dE;
  const float* Sp;
  int HW;
  if (s < 8) { dE = dE1 + (size_t)s * 4096; Sp = S1 + (size_t)s * 4096; HW = 4096; }
  else       { dE = dE2 + (size_t)(s - 8) * 1024; Sp = S2 + (size_t)(s - 8) * 1024; HW = 1024; }
  float t = 0.f;
  for (int i = threadIdx.x; i < HW; i += 256) {
    float dmin = decf(dE[i]);
    float dinv = 1.0f / (dmin + EPS);
    float wmx = __builtin_amdgcn_exp2f((1.0f - dmin * dinv) * KEXP);
    t += wmx / (Sp[i] + EPS);
  }
  __shared__ float red[4];
  t += __shfl_xor(t, 1);  t += __shfl_xor(t, 2);  t += __shfl_xor(t, 4);
  t += __shfl_xor(t, 8);  t += __shfl_xor(t, 16); t += __shfl_xor(t, 32);
  if ((threadIdx.x & 63) == 0) red[threadIdx.x >> 6] = t;
  __syncthreads();
  if (threadIdx.x == 0) {
    float cx = (red[0] + red[1] + red[2] + red[3]) / (float)HW;
    atomicAdd(out, -logf(cx + EPS) * (1.0f / 16.0f));
  }
}

extern "C" void kernel_launch(void* const* d_in, const int* in_sizes, int n_in,
                              void* d_out, int out_size, void* d_ws, size_t ws_size,
                              hipStream_t stream) {
  const float* fx1 = (const float*)d_in[0];  // (8,128,64,64)
  const float* fy1 = (const float*)d_in[1];
  const float* fx2 = (const float*)d_in[2];  // (8,256,32,32)
  const float* fy2 = (const float*)d_in[3];
  float* out = (float*)d_out;

  const int B = 8, HW1 = 4096, HW2 = 1024;

  char* w = (char*)d_ws;
  unsigned* dE1 = (unsigned*)w;                      // 8*4096 u32
  unsigned* dE2 = dE1 + (size_t)B * HW1;             // 8*1024 u32
  float*    S1  = (float*)(dE2 + (size_t)B * HW2);   // 8*4096 f
  float*    S2  = S1 + (size_t)B * HW1;              // 8*1024 f
  uint4*    fx1B = (uint4*)((char*)(S2 + (size_t)B * HW2) + 1024);
  const size_t n1 = (size_t)B * (HW1 / 32) * (128 / 16) * 64;  // 8 MB
  const size_t n2 = (size_t)B * (HW2 / 32) * (256 / 16) * 64;  // 4 MB
  uint4* fy1B = fx1B + n1;
  uint4* fx2B = fy1B + n1;
  uint4* fy2B = fx2B + n2;   // total ~24.4 MB

  prep_all<<<96, 256, 0, stream>>>(fx1, fx1B, fy1, fy1B, fx2, fx2B, fy2, fy2B,
                                   dE1, S1, out);

  passA_all<<<1536, 256, 0, stream>>>(fx1B, fy1B, dE1, fx2B, fy2B, dE2);
  passB_all<<<1536, 256, 0, stream>>>(fx1B, fy1B, dE1, S1, fx2B, fy2B, dE2, S2);

  reduce_out<<<16, 256, 0, stream>>>(dE1, S1, dE2, S2, out);
}

// Round 4
// 181.876 us; speedup vs baseline: 2.5659x; 1.4034x over previous
//
#include <hip/hip_runtime.h>
#include <math.h>

#define EPS 1e-5f
#define KEXP 4.8089834696298780f  // log2(e)/0.3 : exp(x/h) == exp2(x*KEXP)

typedef short short8 __attribute__((ext_vector_type(8)));
typedef float f32x16 __attribute__((ext_vector_type(16)));

static __device__ __forceinline__ unsigned short f2bf(float x) {
  unsigned int b = __float_as_uint(x);
  b += 0x7FFFu + ((b >> 16) & 1u);  // RNE
  return (unsigned short)(b >> 16);
}
static __device__ __forceinline__ unsigned encf(float f) {
  unsigned b = __float_as_uint(f);
  return (b & 0x80000000u) ? ~b : (b | 0x80000000u);
}
static __device__ __forceinline__ float decf(unsigned u) {
  return (u & 0x80000000u) ? __uint_as_float(u & 0x7FFFFFFFu)
                           : __uint_as_float(~u);
}

// async global->LDS, 16B per lane (lane l lands at lds_base + 16*l)
static __device__ __forceinline__ void dma16(const uint4* g, uint4* l) {
  __builtin_amdgcn_global_load_lds(
      (const __attribute__((address_space(1))) unsigned int*)g,
      (__attribute__((address_space(3))) unsigned int*)l, 16, 0, 0);
}

// ---------------------------------------------------------------------------
// prep: normalize column j (over C), cast bf16, write 32x32x16-fragment-blocked:
//   (j,c) -> uint4 idx ((j>>5)*KC + (c>>4))*64 + ((c>>3)&1)*32 + (j&31)
// KC = C/16. Fragment (64 uint4 = 1KB) = 32-row(j) x 16-k tile; lane l holds
// row l&31, k = (l>>5)*8..+8 (verified layout, rounds 0-3 pass).
//
// LATENCY FIX (round-3 lesson: 74us @ 1.9% occupancy with 80 blocks): split
// the C-reduction across 4 waves (c-quarters) per block, combine partial ssq
// via LDS. JPB=64 j per block -> 1280 compute blocks (5/CU, 20 waves/CU).
// Wave q reads row c: 64 consecutive floats = 256B coalesced. Pack phase
// re-reads its c-quarter (L2-hot) and stores 16B/lane coalesced.
// ---------------------------------------------------------------------------
template <int C, int HW, int JPB, int CSPL>
__device__ __forceinline__ void prep_np(const float* __restrict__ f,
                                        uint4* __restrict__ out, int bid,
                                        float* __restrict__ part) {
  constexpr int CPT = C / CSPL;   // channels per thread (layer1:32, layer2:64)
  constexpr int BPS = HW / JPB;   // blocks per sample
  const int t = threadIdx.x;
  const int jj = t % JPB;         // JPB=64: jj = lane, q = wave
  const int q = t / JPB;
  const int b = bid / BPS;
  const int j = (bid % BPS) * JPB + jj;
  const float* p = f + (size_t)b * C * HW + j;
  const int cbase = q * CPT;

  float ssq = 0.f;
#pragma unroll 8
  for (int c = 0; c < CPT; ++c) {
    float v = p[(size_t)(cbase + c) * HW];
    ssq = fmaf(v, v, ssq);
  }
  part[q * JPB + jj] = ssq;
  __syncthreads();
  float tot = 0.f;
#pragma unroll
  for (int r = 0; r < CSPL; ++r) tot += part[r * JPB + jj];
  float inv = 1.0f / (sqrtf(tot) + EPS);

  constexpr int KC = C >> 4;
  uint4* ob = out + (size_t)b * (HW >> 5) * KC * 64 + (size_t)(j >> 5) * KC * 64 + (j & 31);
  for (int c0 = cbase; c0 < cbase + CPT; c0 += 8) {
    unsigned w[4];
#pragma unroll
    for (int h = 0; h < 4; ++h) {
      float v0 = p[(size_t)(c0 + 2 * h) * HW] * inv;
      float v1 = p[(size_t)(c0 + 2 * h + 1) * HW] * inv;
      w[h] = (unsigned)f2bf(v0) | ((unsigned)f2bf(v1) << 16);
    }
    ob[(size_t)(c0 >> 4) * 64 + ((c0 >> 3) & 1) * 32] = make_uint4(w[0], w[1], w[2], w[3]);
  }
}

// prep + init of dE (0xFF), S (0), out (0) in one launch. 1296 blocks.
__global__ __launch_bounds__(256) void prep_all(
    const float* __restrict__ fx1, uint4* __restrict__ fx1B,
    const float* __restrict__ fy1, uint4* __restrict__ fy1B,
    const float* __restrict__ fx2, uint4* __restrict__ fx2B,
    const float* __restrict__ fy2, uint4* __restrict__ fy2B,
    unsigned* __restrict__ dE, float* __restrict__ S, float* __restrict__ out) {
  __shared__ float part[256];
  int bid = blockIdx.x;
  if (bid < 512)        prep_np<128, 4096, 64, 4>(fx1, fx1B, bid, part);
  else if (bid < 1024)  prep_np<128, 4096, 64, 4>(fy1, fy1B, bid - 512, part);
  else if (bid < 1152)  prep_np<256, 1024, 64, 4>(fx2, fx2B, bid - 1024, part);
  else if (bid < 1280)  prep_np<256, 1024, 64, 4>(fy2, fy2B, bid - 1152, part);
  else {
    int t = (bid - 1280) * 256 + threadIdx.x;  // 16 blocks -> 4096 threads
    for (int k = t; k < 8 * (4096 + 1024); k += 4096) {
      dE[k] = 0xFFFFFFFFu;
      S[k] = 0.f;
    }
    if (t == 0) out[0] = 0.f;
  }
}

// ---------------------------------------------------------------------------
// passA body (round-1 exact structure, measured 44us-class): 4 waves, each
// owning TI 32-wide i-tiles; one j-tile per barrier via global_load_lds,
// double-buffered. 32x32x16 MFMA. Scalar smax[TI] only (register discipline).
// ---------------------------------------------------------------------------
template <int HW, int C, int TI, int JSPLIT>
__device__ __forceinline__ void passA_body(
    const uint4* __restrict__ fxB, const uint4* __restrict__ fyB,
    unsigned* __restrict__ dminEnc, int bid, uint4* __restrict__ smem) {
  constexpr int KC = C / 16;        // 16-k chunks (1 KB fragments)
  constexpr int JB = HW / 32;       // 32-wide j-tiles per sample
  constexpr int IBW = 4 * TI;       // 32-wide i-tiles per block
  constexpr int JPS = JB / JSPLIT;  // j-tiles (= steps) per block
  const int lane = threadIdx.x & 63, wv = threadIdx.x >> 6;
  const int sample = bid & 7;       // XCD affinity
  const int rem = bid >> 3;
  const int ib = (rem / JSPLIT) * IBW + wv * TI;
  const int jt0 = (rem % JSPLIT) * JPS;
  const size_t sOff = (size_t)sample * JB * KC * 64;
  const uint4* fx = fxB + sOff;
  const uint4* fy = fyB + sOff;

  auto stage = [&](int jt, int buf) {
    const uint4* g = fy + (size_t)jt * KC * 64;
#pragma unroll
    for (int r = 0; r < KC / 4; ++r) {
      const int t = threadIdx.x + r * 256;
      dma16(g + t, &smem[buf * (KC * 64) + t]);
    }
  };

  stage(jt0, 0);  // prologue DMA

  short8 bf[TI][KC];  // persistent fx fragments (B operand, i = cols of D)
#pragma unroll
  for (int ti = 0; ti < TI; ++ti)
#pragma unroll
    for (int kc = 0; kc < KC; ++kc) {
      uint4 t = fx[(size_t)((ib + ti) * KC + kc) * 64 + lane];
      bf[ti][kc] = *(short8*)&t;
    }

  float smax[TI];
#pragma unroll
  for (int ti = 0; ti < TI; ++ti) smax[ti] = -1e30f;

  for (int s = 0; s < JPS; ++s) {
    const int cur = s & 1;
    __syncthreads();                       // tile s ready; prev reads done
    if (s + 1 < JPS) stage(jt0 + s + 1, cur ^ 1);

    f32x16 acc[TI];
#pragma unroll
    for (int ti = 0; ti < TI; ++ti)
#pragma unroll
      for (int r = 0; r < 16; ++r) acc[ti][r] = 0.f;
#pragma unroll
    for (int kc = 0; kc < KC; ++kc) {
      uint4 t = smem[cur * (KC * 64) + kc * 64 + lane];
      short8 a = *(short8*)&t;
#pragma unroll
      for (int ti = 0; ti < TI; ++ti)
        acc[ti] = __builtin_amdgcn_mfma_f32_32x32x16_bf16(a, bf[ti][kc], acc[ti], 0, 0, 0);
    }
#pragma unroll
    for (int ti = 0; ti < TI; ++ti)
#pragma unroll
      for (int r = 0; r < 16; ++r) smax[ti] = fmaxf(smax[ti], acc[ti][r]);
  }

  // rows j live in regs + lane bit5 -> one xor-32 hop; cols i = lane&31
#pragma unroll
  for (int ti = 0; ti < TI; ++ti) {
    float v = smax[ti];
    v = fmaxf(v, __shfl_xor(v, 32));
    if (lane < 32)
      atomicMin(&dminEnc[(size_t)sample * HW + (ib + ti) * 32 + lane],
                encf(1.0f - v));
  }
}

// ---------------------------------------------------------------------------
// passB body: recompute dots, partial sum_j exp2(c0 + sim*c1).
// ---------------------------------------------------------------------------
template <int HW, int C, int TI, int JSPLIT>
__device__ __forceinline__ void passB_body(
    const uint4* __restrict__ fxB, const uint4* __restrict__ fyB,
    const unsigned* __restrict__ dminEnc, float* __restrict__ Ssum,
    int bid, uint4* __restrict__ smem) {
  constexpr int KC = C / 16;
  constexpr int JB = HW / 32;
  constexpr int IBW = 4 * TI;
  constexpr int JPS = JB / JSPLIT;
  const int lane = threadIdx.x & 63, wv = threadIdx.x >> 6;
  const int sample = bid & 7;
  const int rem = bid >> 3;
  const int ib = (rem / JSPLIT) * IBW + wv * TI;
  const int jt0 = (rem % JSPLIT) * JPS;
  const size_t sOff = (size_t)sample * JB * KC * 64;
  const uint4* fx = fxB + sOff;
  const uint4* fy = fyB + sOff;

  auto stage = [&](int jt, int buf) {
    const uint4* g = fy + (size_t)jt * KC * 64;
#pragma unroll
    for (int r = 0; r < KC / 4; ++r) {
      const int t = threadIdx.x + r * 256;
      dma16(g + t, &smem[buf * (KC * 64) + t]);
    }
  };

  stage(jt0, 0);

  short8 bf[TI][KC];
#pragma unroll
  for (int ti = 0; ti < TI; ++ti)
#pragma unroll
    for (int kc = 0; kc < KC; ++kc) {
      uint4 t = fx[(size_t)((ib + ti) * KC + kc) * 64 + lane];
      bf[ti][kc] = *(short8*)&t;
    }

  float c0v[TI], c1v[TI];
#pragma unroll
  for (int ti = 0; ti < TI; ++ti) {
    float dmin = decf(dminEnc[(size_t)sample * HW + (ib + ti) * 32 + (lane & 31)]);
    float dinv = 1.0f / (dmin + EPS);
    c1v[ti] = dinv * KEXP;
    c0v[ti] = (1.0f - dinv) * KEXP;
  }

  float ssum[TI];
#pragma unroll
  for (int ti = 0; ti < TI; ++ti) ssum[ti] = 0.f;

  for (int s = 0; s < JPS; ++s) {
    const int cur = s & 1;
    __syncthreads();
    if (s + 1 < JPS) stage(jt0 + s + 1, cur ^ 1);

    f32x16 acc[TI];
#pragma unroll
    for (int ti = 0; ti < TI; ++ti)
#pragma unroll
      for (int r = 0; r < 16; ++r) acc[ti][r] = 0.f;
#pragma unroll
    for (int kc = 0; kc < KC; ++kc) {
      uint4 t = smem[cur * (KC * 64) + kc * 64 + lane];
      short8 a = *(short8*)&t;
#pragma unroll
      for (int ti = 0; ti < TI; ++ti)
        acc[ti] = __builtin_amdgcn_mfma_f32_32x32x16_bf16(a, bf[ti][kc], acc[ti], 0, 0, 0);
    }
#pragma unroll
    for (int ti = 0; ti < TI; ++ti)
#pragma unroll
      for (int r = 0; r < 16; ++r)
        ssum[ti] += __builtin_amdgcn_exp2f(fmaf(acc[ti][r], c1v[ti], c0v[ti]));
  }

#pragma unroll
  for (int ti = 0; ti < TI; ++ti) {
    float v = ssum[ti];
    v += __shfl_xor(v, 32);
    if (lane < 32)
      atomicAdd(&Ssum[(size_t)sample * HW + (ib + ti) * 32 + lane], v);
  }
}

// ---------------------------------------------------------------------------
// Fused launches: layer1 (1024 blocks) + layer2 (512 blocks) in one grid.
// LDS: 32KB/block (layer2's 2x16KB dbuf), 4 blocks/CU = 128KB <= 160KB.
// layer1: TI=2 -> block i-width 256; JSPLIT=8 -> JPS=16 steps
// layer2: TI=1 -> block i-width 128; JSPLIT=8 -> JPS=4  steps
// ---------------------------------------------------------------------------
__global__ __launch_bounds__(256, 4) void passA_all(
    const uint4* __restrict__ fx1B, const uint4* __restrict__ fy1B,
    unsigned* __restrict__ dE1,
    const uint4* __restrict__ fx2B, const uint4* __restrict__ fy2B,
    unsigned* __restrict__ dE2) {
  __shared__ uint4 smem[2048];  // 32 KB
  if (blockIdx.x < 1024)
    passA_body<4096, 128, 2, 8>(fx1B, fy1B, dE1, blockIdx.x, smem);
  else
    passA_body<1024, 256, 1, 8>(fx2B, fy2B, dE2, blockIdx.x - 1024, smem);
}

__global__ __launch_bounds__(256, 4) void passB_all(
    const uint4* __restrict__ fx1B, const uint4* __restrict__ fy1B,
    const unsigned* __restrict__ dE1, float* __restrict__ S1,
    const uint4* __restrict__ fx2B, const uint4* __restrict__ fy2B,
    const unsigned* __restrict__ dE2, float* __restrict__ S2) {
  __shared__ uint4 smem[2048];
  if (blockIdx.x < 1024)
    passB_body<4096, 128, 2, 8>(fx1B, fy1B, dE1, S1, blockIdx.x, smem);
  else
    passB_body<1024, 256, 1, 8>(fx2B, fy2B, dE2, S2, blockIdx.x - 1024, smem);
}

// ---------------------------------------------------------------------------
// reduce_out: one block per sample; atomicAdd(-log(cx+EPS)/16) into out[0].
// ---------------------------------------------------------------------------
__global__ __launch_bounds__(256) void reduce_out(
    const unsigned* __restrict__ dE1, const float* __restrict__ S1,
    const unsigned* __restrict__ dE2, const float* __restrict__ S2,
    float* __restrict__ out) {
  const int s = blockIdx.x;
  const unsigned* dE;
  const float* Sp;
  int HW;
  if (s < 8) { dE = dE1 + (size_t)s * 4096; Sp = S1 + (size_t)s * 4096; HW = 4096; }
  else       { dE = dE2 + (size_t)(s - 8) * 1024; Sp = S2 + (size_t)(s - 8) * 1024; HW = 1024; }
  float t = 0.f;
  for (int i = threadIdx.x; i < HW; i += 256) {
    float dmin = decf(dE[i]);
    float dinv = 1.0f / (dmin + EPS);
    float wmx = __builtin_amdgcn_exp2f((1.0f - dmin * dinv) * KEXP);
    t += wmx / (Sp[i] + EPS);
  }
  __shared__ float red[4];
  t += __shfl_xor(t, 1);  t += __shfl_xor(t, 2);  t += __shfl_xor(t, 4);
  t += __shfl_xor(t, 8);  t += __shfl_xor(t, 16); t += __shfl_xor(t, 32);
  if ((threadIdx.x & 63) == 0) red[threadIdx.x >> 6] = t;
  __syncthreads();
  if (threadIdx.x == 0) {
    float cx = (red[0] + red[1] + red[2] + red[3]) / (float)HW;
    atomicAdd(out, -logf(cx + EPS) * (1.0f / 16.0f));
  }
}

extern "C" void kernel_launch(void* const* d_in, const int* in_sizes, int n_in,
                              void* d_out, int out_size, void* d_ws, size_t ws_size,
                              hipStream_t stream) {
  const float* fx1 = (const float*)d_in[0];  // (8,128,64,64)
  const float* fy1 = (const float*)d_in[1];
  const float* fx2 = (const float*)d_in[2];  // (8,256,32,32)
  const float* fy2 = (const float*)d_in[3];
  float* out = (float*)d_out;

  const int B = 8, HW1 = 4096, HW2 = 1024;

  char* w = (char*)d_ws;
  unsigned* dE1 = (unsigned*)w;                      // 8*4096 u32
  unsigned* dE2 = dE1 + (size_t)B * HW1;             // 8*1024 u32
  float*    S1  = (float*)(dE2 + (size_t)B * HW2);   // 8*4096 f
  float*    S2  = S1 + (size_t)B * HW1;              // 8*1024 f
  uint4*    fx1B = (uint4*)((char*)(S2 + (size_t)B * HW2) + 1024);
  const size_t n1 = (size_t)B * (HW1 / 32) * (128 / 16) * 64;  // 8 MB
  const size_t n2 = (size_t)B * (HW2 / 32) * (256 / 16) * 64;  // 4 MB
  uint4* fy1B = fx1B + n1;
  uint4* fx2B = fy1B + n1;
  uint4* fy2B = fx2B + n2;   // total ~24.4 MB

  prep_all<<<1296, 256, 0, stream>>>(fx1, fx1B, fy1, fy1B, fx2, fx2B, fy2, fy2B,
                                     dE1, S1, out);

  passA_all<<<1536, 256, 0, stream>>>(fx1B, fy1B, dE1, fx2B, fy2B, dE2);
  passB_all<<<1536, 256, 0, stream>>>(fx1B, fy1B, dE1, S1, fx2B, fy2B, dE2, S2);

  reduce_out<<<16, 256, 0, stream>>>(dE1, S1, dE2, S2, out);
}

// Round 5
// 169.572 us; speedup vs baseline: 2.7521x; 1.0726x over previous
//
#include <hip/hip_runtime.h>
#include <math.h>

#define EPS 1e-5f
#define KEXP 4.8089834696298780f  // log2(e)/0.3 : exp(x/h) == exp2(x*KEXP)

typedef short short8 __attribute__((ext_vector_type(8)));
typedef float f32x16 __attribute__((ext_vector_type(16)));

static __device__ __forceinline__ unsigned short f2bf(float x) {
  unsigned int b = __float_as_uint(x);
  b += 0x7FFFu + ((b >> 16) & 1u);  // RNE
  return (unsigned short)(b >> 16);
}
static __device__ __forceinline__ unsigned encf(float f) {
  unsigned b = __float_as_uint(f);
  return (b & 0x80000000u) ? ~b : (b | 0x80000000u);
}
static __device__ __forceinline__ float decf(unsigned u) {
  return (u & 0x80000000u) ? __uint_as_float(u & 0x7FFFFFFFu)
                           : __uint_as_float(~u);
}

// async global->LDS, 16B per lane (lane l lands at lds_base + 16*l)
static __device__ __forceinline__ void dma16(const uint4* g, uint4* l) {
  __builtin_amdgcn_global_load_lds(
      (const __attribute__((address_space(1))) unsigned int*)g,
      (__attribute__((address_space(3))) unsigned int*)l, 16, 0, 0);
}

// ---------------------------------------------------------------------------
// prep: normalize column j (over C), cast bf16, write 32x32x16-fragment-blocked:
//   (j,c) -> uint4 idx ((j>>5)*KC + (c>>4))*64 + ((c>>3)&1)*32 + (j&31)
// KC = C/16. Fragment (64 uint4 = 1KB) = 32-row(j) x 16-k tile; lane l holds
// row l&31, k = (l>>5)*8..+8 (verified layout, rounds 0-4 pass).
//
// v3 (single-read): each thread keeps its CPT=32 channels IN REGISTERS —
// ssq from regs, LDS-combine across CSPL c-groups, pack from regs. No
// second global read (round-4 version re-read 75 MB through L2).
// ---------------------------------------------------------------------------
template <int C, int HW, int JPB, int CSPL>
__device__ __forceinline__ void prep_np2(const float* __restrict__ f,
                                         uint4* __restrict__ out, int bid,
                                         float* __restrict__ part) {
  constexpr int CPT = C / CSPL;   // 32 channels per thread (both layers)
  constexpr int BPS = HW / JPB;   // blocks per sample
  const int t = threadIdx.x;
  const int jj = t % JPB;
  const int q = t / JPB;
  const int b = bid / BPS;
  const int j = (bid % BPS) * JPB + jj;
  const float* p = f + (size_t)b * C * HW + j;
  const int cbase = q * CPT;

  float vreg[CPT];
  float ssq = 0.f;
#pragma unroll
  for (int c = 0; c < CPT; ++c) {
    vreg[c] = p[(size_t)(cbase + c) * HW];
    ssq = fmaf(vreg[c], vreg[c], ssq);
  }
  part[q * JPB + jj] = ssq;
  __syncthreads();
  float tot = 0.f;
#pragma unroll
  for (int r = 0; r < CSPL; ++r) tot += part[r * JPB + jj];
  float inv = 1.0f / (sqrtf(tot) + EPS);

  constexpr int KC = C >> 4;
  uint4* ob = out + (size_t)b * (HW >> 5) * KC * 64 + (size_t)(j >> 5) * KC * 64 + (j & 31);
#pragma unroll
  for (int c0 = 0; c0 < CPT; c0 += 8) {
    unsigned w[4];
#pragma unroll
    for (int h = 0; h < 4; ++h)
      w[h] = (unsigned)f2bf(vreg[c0 + 2 * h] * inv) |
             ((unsigned)f2bf(vreg[c0 + 2 * h + 1] * inv) << 16);
    const int cg = cbase + c0;
    ob[(size_t)(cg >> 4) * 64 + ((cg >> 3) & 1) * 32] = make_uint4(w[0], w[1], w[2], w[3]);
  }
}

// prep + init of dE (0xFF), S (0), out (0) in one launch. 1552 blocks.
__global__ __launch_bounds__(256) void prep_all(
    const float* __restrict__ fx1, uint4* __restrict__ fx1B,
    const float* __restrict__ fy1, uint4* __restrict__ fy1B,
    const float* __restrict__ fx2, uint4* __restrict__ fx2B,
    const float* __restrict__ fy2, uint4* __restrict__ fy2B,
    unsigned* __restrict__ dE, float* __restrict__ S, float* __restrict__ out) {
  __shared__ float part[256];
  int bid = blockIdx.x;
  if (bid < 512)        prep_np2<128, 4096, 64, 4>(fx1, fx1B, bid, part);
  else if (bid < 1024)  prep_np2<128, 4096, 64, 4>(fy1, fy1B, bid - 512, part);
  else if (bid < 1280)  prep_np2<256, 1024, 32, 8>(fx2, fx2B, bid - 1024, part);
  else if (bid < 1536)  prep_np2<256, 1024, 32, 8>(fy2, fy2B, bid - 1280, part);
  else {
    int t = (bid - 1536) * 256 + threadIdx.x;  // 16 blocks -> 4096 threads
    for (int k = t; k < 8 * (4096 + 1024); k += 4096) {
      dE[k] = 0xFFFFFFFFu;
      S[k] = 0.f;
    }
    if (t == 0) out[0] = 0.f;
  }
}

// ---------------------------------------------------------------------------
// passA body: 4 waves, each owning TI 32-wide i-tiles. fy streamed in uniform
// 8 KB phase-slabs through a 3-buffer LDS ring with COUNTED vmcnt + raw
// s_barrier (T3/T4): loads stay up to 2 phases in flight, never drained to 0
// in steady state. PH = k-phases per j-tile (layer1: 1, layer2: 2; acc
// carried across phases, bf index statically unrolled).
// Ring safety: at the barrier of phase p, all waves have finished reading
// buf (p-1)%3 (their phase p-1 reads completed before they arrived), so
// stage(p+2) -> buf (p+2)%3 == (p-1)%3 after the barrier is safe; vmcnt(2)
// (= the 2 in-flight loads of stage p+1) guarantees stage p has landed
// (vmcnt retires oldest-first).
// ---------------------------------------------------------------------------
template <int HW, int C, int TI, int JSPLIT, int PH>
__device__ __forceinline__ void passA_body(
    const uint4* __restrict__ fxB, const uint4* __restrict__ fyB,
    unsigned* __restrict__ dminEnc, int bid, uint4* __restrict__ smem) {
  constexpr int KC = C / 16;        // chunks per j-tile (8 or 16)
  constexpr int JB = HW / 32;       // 32-wide j-tiles per sample
  constexpr int IBW = 4 * TI;       // 32-wide i-tiles per block
  constexpr int JPS = JB / JSPLIT;  // j-tiles per block
  constexpr int NPH = JPS * PH;     // total phases (8 KB slabs)
  static_assert(KC / PH == 8, "phase slab must be 8 chunks");
  const int lane = threadIdx.x & 63, wv = threadIdx.x >> 6;
  const int sample = bid & 7;       // XCD affinity
  const int rem = bid >> 3;
  const int ib = (rem / JSPLIT) * IBW + wv * TI;
  const int jt0 = (rem % JSPLIT) * JPS;
  const size_t sOff = (size_t)sample * JB * KC * 64;
  const uint4* fx = fxB + sOff;
  const uint4* fy = fyB + sOff;
  const uint4* g0 = fy + (size_t)jt0 * KC * 64;  // phases = consecutive 512-uint4 slabs

  auto stageP = [&](int p, int bf3) {
#pragma unroll
    for (int r = 0; r < 2; ++r) {
      const int tt = threadIdx.x + r * 256;
      dma16(g0 + (size_t)p * 512 + tt, &smem[bf3 * 512 + tt]);
    }
  };

  stageP(0, 0);
  stageP(1, 1);

  short8 bf[TI][KC];  // persistent fx fragments (B operand, i = cols of D)
#pragma unroll
  for (int ti = 0; ti < TI; ++ti)
#pragma unroll
    for (int kc = 0; kc < KC; ++kc) {
      uint4 t = fx[(size_t)((ib + ti) * KC + kc) * 64 + lane];
      bf[ti][kc] = *(short8*)&t;
    }

  float smax[TI];
#pragma unroll
  for (int ti = 0; ti < TI; ++ti) smax[ti] = -1e30f;

  int bufc = 0, bufs = 2;  // = p%3, (p+2)%3
  for (int tj = 0; tj < JPS; ++tj) {
    f32x16 acc[TI];
#pragma unroll
    for (int ti = 0; ti < TI; ++ti)
#pragma unroll
      for (int r = 0; r < 16; ++r) acc[ti][r] = 0.f;
#pragma unroll
    for (int h = 0; h < PH; ++h) {
      const int p = tj * PH + h;
      if (p + 1 < NPH) asm volatile("s_waitcnt vmcnt(2)" ::: "memory");
      else             asm volatile("s_waitcnt vmcnt(0)" ::: "memory");
      __builtin_amdgcn_s_barrier();
      __builtin_amdgcn_sched_barrier(0);
      if (p + 2 < NPH) stageP(p + 2, bufs);
      __builtin_amdgcn_s_setprio(1);
#pragma unroll
      for (int kc = 0; kc < 8; ++kc) {
        uint4 t = smem[bufc * 512 + kc * 64 + lane];
        short8 a = *(short8*)&t;
#pragma unroll
        for (int ti = 0; ti < TI; ++ti)
          acc[ti] = __builtin_amdgcn_mfma_f32_32x32x16_bf16(a, bf[ti][h * 8 + kc], acc[ti], 0, 0, 0);
      }
      __builtin_amdgcn_s_setprio(0);
      bufc = bufc == 2 ? 0 : bufc + 1;
      bufs = bufs == 2 ? 0 : bufs + 1;
    }
    // immediate scalar reduction: acc dies here (register discipline)
#pragma unroll
    for (int ti = 0; ti < TI; ++ti)
#pragma unroll
      for (int r = 0; r < 16; ++r) smax[ti] = fmaxf(smax[ti], acc[ti][r]);
  }

  // rows j live in regs + lane bit5 -> one xor-32 hop; cols i = lane&31
#pragma unroll
  for (int ti = 0; ti < TI; ++ti) {
    float v = smax[ti];
    v = fmaxf(v, __shfl_xor(v, 32));
    if (lane < 32)
      atomicMin(&dminEnc[(size_t)sample * HW + (ib + ti) * 32 + lane],
                encf(1.0f - v));
  }
}

// ---------------------------------------------------------------------------
// passB body: same ring pipeline; per-tile epilogue sum_j exp2(c0 + sim*c1).
// ---------------------------------------------------------------------------
template <int HW, int C, int TI, int JSPLIT, int PH>
__device__ __forceinline__ void passB_body(
    const uint4* __restrict__ fxB, const uint4* __restrict__ fyB,
    const unsigned* __restrict__ dminEnc, float* __restrict__ Ssum,
    int bid, uint4* __restrict__ smem) {
  constexpr int KC = C / 16;
  constexpr int JB = HW / 32;
  constexpr int IBW = 4 * TI;
  constexpr int JPS = JB / JSPLIT;
  constexpr int NPH = JPS * PH;
  static_assert(KC / PH == 8, "phase slab must be 8 chunks");
  const int lane = threadIdx.x & 63, wv = threadIdx.x >> 6;
  const int sample = bid & 7;
  const int rem = bid >> 3;
  const int ib = (rem / JSPLIT) * IBW + wv * TI;
  const int jt0 = (rem % JSPLIT) * JPS;
  const size_t sOff = (size_t)sample * JB * KC * 64;
  const uint4* fx = fxB + sOff;
  const uint4* fy = fyB + sOff;
  const uint4* g0 = fy + (size_t)jt0 * KC * 64;

  auto stageP = [&](int p, int bf3) {
#pragma unroll
    for (int r = 0; r < 2; ++r) {
      const int tt = threadIdx.x + r * 256;
      dma16(g0 + (size_t)p * 512 + tt, &smem[bf3 * 512 + tt]);
    }
  };

  stageP(0, 0);
  stageP(1, 1);

  short8 bf[TI][KC];
#pragma unroll
  for (int ti = 0; ti < TI; ++ti)
#pragma unroll
    for (int kc = 0; kc < KC; ++kc) {
      uint4 t = fx[(size_t)((ib + ti) * KC + kc) * 64 + lane];
      bf[ti][kc] = *(short8*)&t;
    }

  float c0v[TI], c1v[TI];
#pragma unroll
  for (int ti = 0; ti < TI; ++ti) {
    float dmin = decf(dminEnc[(size_t)sample * HW + (ib + ti) * 32 + (lane & 31)]);
    float dinv = 1.0f / (dmin + EPS);
    c1v[ti] = dinv * KEXP;
    c0v[ti] = (1.0f - dinv) * KEXP;
  }

  float ssum[TI];
#pragma unroll
  for (int ti = 0; ti < TI; ++ti) ssum[ti] = 0.f;

  int bufc = 0, bufs = 2;
  for (int tj = 0; tj < JPS; ++tj) {
    f32x16 acc[TI];
#pragma unroll
    for (int ti = 0; ti < TI; ++ti)
#pragma unroll
      for (int r = 0; r < 16; ++r) acc[ti][r] = 0.f;
#pragma unroll
    for (int h = 0; h < PH; ++h) {
      const int p = tj * PH + h;
      if (p + 1 < NPH) asm volatile("s_waitcnt vmcnt(2)" ::: "memory");
      else             asm volatile("s_waitcnt vmcnt(0)" ::: "memory");
      __builtin_amdgcn_s_barrier();
      __builtin_amdgcn_sched_barrier(0);
      if (p + 2 < NPH) stageP(p + 2, bufs);
      __builtin_amdgcn_s_setprio(1);
#pragma unroll
      for (int kc = 0; kc < 8; ++kc) {
        uint4 t = smem[bufc * 512 + kc * 64 + lane];
        short8 a = *(short8*)&t;
#pragma unroll
        for (int ti = 0; ti < TI; ++ti)
          acc[ti] = __builtin_amdgcn_mfma_f32_32x32x16_bf16(a, bf[ti][h * 8 + kc], acc[ti], 0, 0, 0);
      }
      __builtin_amdgcn_s_setprio(0);
      bufc = bufc == 2 ? 0 : bufc + 1;
      bufs = bufs == 2 ? 0 : bufs + 1;
    }
#pragma unroll
    for (int ti = 0; ti < TI; ++ti)
#pragma unroll
      for (int r = 0; r < 16; ++r)
        ssum[ti] += __builtin_amdgcn_exp2f(fmaf(acc[ti][r], c1v[ti], c0v[ti]));
  }

#pragma unroll
  for (int ti = 0; ti < TI; ++ti) {
    float v = ssum[ti];
    v += __shfl_xor(v, 32);
    if (lane < 32)
      atomicAdd(&Ssum[(size_t)sample * HW + (ib + ti) * 32 + lane], v);
  }
}

// ---------------------------------------------------------------------------
// Fused launches: layer1 (1024 blocks, PH=1, 16 phases) + layer2 (512 blocks,
// PH=2, 8 phases) in one grid. LDS: 3 x 8 KB ring = 24 KB/block.
// ---------------------------------------------------------------------------
__global__ __launch_bounds__(256, 4) void passA_all(
    const uint4* __restrict__ fx1B, const uint4* __restrict__ fy1B,
    unsigned* __restrict__ dE1,
    const uint4* __restrict__ fx2B, const uint4* __restrict__ fy2B,
    unsigned* __restrict__ dE2) {
  __shared__ uint4 smem[1536];  // 24 KB: 3-buffer ring
  if (blockIdx.x < 1024)
    passA_body<4096, 128, 2, 8, 1>(fx1B, fy1B, dE1, blockIdx.x, smem);
  else
    passA_body<1024, 256, 1, 8, 2>(fx2B, fy2B, dE2, blockIdx.x - 1024, smem);
}

__global__ __launch_bounds__(256, 4) void passB_all(
    const uint4* __restrict__ fx1B, const uint4* __restrict__ fy1B,
    const unsigned* __restrict__ dE1, float* __restrict__ S1,
    const uint4* __restrict__ fx2B, const uint4* __restrict__ fy2B,
    const unsigned* __restrict__ dE2, float* __restrict__ S2) {
  __shared__ uint4 smem[1536];
  if (blockIdx.x < 1024)
    passB_body<4096, 128, 2, 8, 1>(fx1B, fy1B, dE1, S1, blockIdx.x, smem);
  else
    passB_body<1024, 256, 1, 8, 2>(fx2B, fy2B, dE2, S2, blockIdx.x - 1024, smem);
}

// ---------------------------------------------------------------------------
// reduce_out: one block per sample; atomicAdd(-log(cx+EPS)/16) into out[0].
// ---------------------------------------------------------------------------
__global__ __launch_bounds__(256) void reduce_out(
    const unsigned* __restrict__ dE1, const float* __restrict__ S1,
    const unsigned* __restrict__ dE2, const float* __restrict__ S2,
    float* __restrict__ out) {
  const int s = blockIdx.x;
  const unsigned* dE;
  const float* Sp;
  int HW;
  if (s < 8) { dE = dE1 + (size_t)s * 4096; Sp = S1 + (size_t)s * 4096; HW = 4096; }
  else       { dE = dE2 + (size_t)(s - 8) * 1024; Sp = S2 + (size_t)(s - 8) * 1024; HW = 1024; }
  float t = 0.f;
  for (int i = threadIdx.x; i < HW; i += 256) {
    float dmin = decf(dE[i]);
    float dinv = 1.0f / (dmin + EPS);
    float wmx = __builtin_amdgcn_exp2f((1.0f - dmin * dinv) * KEXP);
    t += wmx / (Sp[i] + EPS);
  }
  __shared__ float red[4];
  t += __shfl_xor(t, 1);  t += __shfl_xor(t, 2);  t += __shfl_xor(t, 4);
  t += __shfl_xor(t, 8);  t += __shfl_xor(t, 16); t += __shfl_xor(t, 32);
  if ((threadIdx.x & 63) == 0) red[threadIdx.x >> 6] = t;
  __syncthreads();
  if (threadIdx.x == 0) {
    float cx = (red[0] + red[1] + red[2] + red[3]) / (float)HW;
    atomicAdd(out, -logf(cx + EPS) * (1.0f / 16.0f));
  }
}

extern "C" void kernel_launch(void* const* d_in, const int* in_sizes, int n_in,
                              void* d_out, int out_size, void* d_ws, size_t ws_size,
                              hipStream_t stream) {
  const float* fx1 = (const float*)d_in[0];  // (8,128,64,64)
  const float* fy1 = (const float*)d_in[1];
  const float* fx2 = (const float*)d_in[2];  // (8,256,32,32)
  const float* fy2 = (const float*)d_in[3];
  float* out = (float*)d_out;

  const int B = 8, HW1 = 4096, HW2 = 1024;

  char* w = (char*)d_ws;
  unsigned* dE1 = (unsigned*)w;                      // 8*4096 u32
  unsigned* dE2 = dE1 + (size_t)B * HW1;             // 8*1024 u32
  float*    S1  = (float*)(dE2 + (size_t)B * HW2);   // 8*4096 f
  float*    S2  = S1 + (size_t)B * HW1;              // 8*1024 f
  uint4*    fx1B = (uint4*)((char*)(S2 + (size_t)B * HW2) + 1024);
  const size_t n1 = (size_t)B * (HW1 / 32) * (128 / 16) * 64;  // 8 MB
  const size_t n2 = (size_t)B * (HW2 / 32) * (256 / 16) * 64;  // 4 MB
  uint4* fy1B = fx1B + n1;
  uint4* fx2B = fy1B + n1;
  uint4* fy2B = fx2B + n2;   // total ~24.4 MB

  prep_all<<<1552, 256, 0, stream>>>(fx1, fx1B, fy1, fy1B, fx2, fx2B, fy2, fy2B,
                                     dE1, S1, out);

  passA_all<<<1536, 256, 0, stream>>>(fx1B, fy1B, dE1, fx2B, fy2B, dE2);
  passB_all<<<1536, 256, 0, stream>>>(fx1B, fy1B, dE1, S1, fx2B, fy2B, dE2, S2);

  reduce_out<<<16, 256, 0, stream>>>(dE1, S1, dE2, S2, out);
}